// Round 4
// baseline (225.203 us; speedup 1.0000x reference)
//
#include <hip/hip_runtime.h>
#include <stdint.h>

#define M_DIM 8192
#define N_DIM 4096
#define K_DIM 4096
#define NT (K_DIM / 128)  // 32 k-tiles of 128 fp8 bytes

typedef float f32x4 __attribute__((ext_vector_type(4)));
typedef int v4i __attribute__((ext_vector_type(4)));
typedef int v8i __attribute__((ext_vector_type(8)));
typedef uint32_t u32;

// ---------- helpers ----------

__device__ __forceinline__ void gload_lds16(const void* g, void* l) {
  __builtin_amdgcn_global_load_lds(
      (__attribute__((address_space(1))) void*)(g),
      (__attribute__((address_space(3))) void*)(l), 16, 0, 0);
}

__device__ __forceinline__ float clipdiv(float v, float s) {
  v = v / s;
  return fminf(fmaxf(v, -448.f), 448.f);
}

__device__ __forceinline__ u32 pack4_fp8(float a, float b, float c, float d) {
  int w = __builtin_amdgcn_cvt_pk_fp8_f32(a, b, 0, false);
  w = __builtin_amdgcn_cvt_pk_fp8_f32(c, d, w, true);
  return (u32)w;
}

// ---------- quantize A (row-major M x K, f32 -> e4m3fn) ----------

__global__ __launch_bounds__(256) void quant_a(const float* __restrict__ x,
                                               u32* __restrict__ q,
                                               const float* __restrict__ scale,
                                               int nv4) {
  int base = blockIdx.x * 1024 + threadIdx.x;
  float s = scale[0];
#pragma unroll
  for (int r = 0; r < 4; ++r) {
    int idx = base + r * 256;
    if (idx < nv4) {
      float4 v = ((const float4*)x)[idx];
      q[idx] = pack4_fp8(clipdiv(v.x, s), clipdiv(v.y, s),
                         clipdiv(v.z, s), clipdiv(v.w, s));
    }
  }
}

// ---------- quantize + transpose B (K x N f32 -> N x K fp8) ----------

__global__ __launch_bounds__(256) void quant_b_t(const float* __restrict__ B,
                                                 uint8_t* __restrict__ qT,
                                                 const float* __restrict__ scale) {
  __shared__ __align__(16) uint8_t lt[64 * 80];
  int tid = threadIdx.x;
  int kt = blockIdx.x * 64;
  int nt = blockIdx.y * 64;
  float s = scale[0];

  int kl = tid >> 4;
  int n4 = (tid & 15) * 4;
#pragma unroll
  for (int rep = 0; rep < 4; ++rep) {
    int k = kl + rep * 16;
    float4 v = *(const float4*)&B[(long)(kt + k) * N_DIM + nt + n4];
    u32 w = pack4_fp8(clipdiv(v.x, s), clipdiv(v.y, s),
                      clipdiv(v.z, s), clipdiv(v.w, s));
    lt[(n4 + 0) * 80 + k] = (uint8_t)(w & 0xff);
    lt[(n4 + 1) * 80 + k] = (uint8_t)((w >> 8) & 0xff);
    lt[(n4 + 2) * 80 + k] = (uint8_t)((w >> 16) & 0xff);
    lt[(n4 + 3) * 80 + k] = (uint8_t)(w >> 24);
  }
  __syncthreads();
  int n = tid >> 2, ch = tid & 3;
  uint4 o = *(const uint4*)&lt[n * 80 + ch * 16];
  *(uint4*)&qT[(long)(nt + n) * K_DIM + kt + ch * 16] = o;
}

// ---------- 256x256 8-phase MX-fp8 GEMM ----------
// 8 waves (2M x 4N), BK=128 B, double-buffered 128 KiB LDS.
// Quadrant order per tile: (0,0),(0,1),(1,1),(1,0) — frees one LDS slot/phase.
// Stage stream (1 half-tile per phase, slot's last reader always in a PRIOR
// barrier-separated phase -> WAR is barrier-ordered, not latency-covered):
//   P1: Ah1(T+1)->b1   P2: Bh0(T+1)->b1   P3: Ah0(T+2)->b0   P4: Bh1(T+2)->b0
//   P5: Ah1(T+2)->b0   P6: Bh0(T+2)->b0   P7: Ah0(T+3)->b1   P8: Bh1(T+3)->b1
// vmcnt(4) at P4 completes exactly tile T+1 (FIFO oldest 8 of 12);
// vmcnt(4) at P8 completes exactly tile T+2.

template <int Q, int MQ, int NQ, int BUF, int SMAT, int SH, int SBUF, int VM>
__device__ __forceinline__ void phase(uint8_t* lds, const int (&offA)[4][2],
                                      const int (&offB)[2][2],
                                      f32x4 (&acc)[4][4][2], int st,
                                      const uint8_t* pA0, const uint8_t* pA1,
                                      const uint8_t* pB0, const uint8_t* pB1,
                                      int ld0, int ld1) {
  const uint8_t* Ab = lds + BUF * 32768 + MQ * 16384;
  const uint8_t* Bb = lds + 65536 + BUF * 32768 + NQ * 16384;
  v8i a[4], b[2];
#pragma unroll
  for (int mi = 0; mi < 4; ++mi) {
    v4i lo = *(const v4i*)(Ab + offA[mi][0]);
    v4i hi = *(const v4i*)(Ab + offA[mi][1]);
    a[mi] = __builtin_shufflevector(lo, hi, 0, 1, 2, 3, 4, 5, 6, 7);
  }
#pragma unroll
  for (int nj = 0; nj < 2; ++nj) {
    v4i lo = *(const v4i*)(Bb + offB[nj][0]);
    v4i hi = *(const v4i*)(Bb + offB[nj][1]);
    b[nj] = __builtin_shufflevector(lo, hi, 0, 1, 2, 3, 4, 5, 6, 7);
  }
  // stage one half-tile (2 x 16B per thread)
  {
    long ko = (long)((st & (NT - 1)) * 128) + (long)SH * (128L * (long)K_DIM);
    const uint8_t* s0 = (SMAT ? pB0 : pA0) + ko;
    const uint8_t* s1 = (SMAT ? pB1 : pA1) + ko;
    uint8_t* d0 = lds + SMAT * 65536 + SBUF * 32768 + SH * 16384 + ld0;
    uint8_t* d1 = lds + SMAT * 65536 + SBUF * 32768 + SH * 16384 + ld1;
    gload_lds16(s0, d0);
    gload_lds16(s1, d1);
  }
  asm volatile("s_waitcnt lgkmcnt(8)" ::: "memory");
  __builtin_amdgcn_s_barrier();
  asm volatile("s_waitcnt lgkmcnt(0)" ::: "memory");
  __builtin_amdgcn_sched_barrier(0);
  __builtin_amdgcn_s_setprio(1);
#pragma unroll
  for (int mi = 0; mi < 4; ++mi)
#pragma unroll
    for (int nj = 0; nj < 2; ++nj)
      acc[Q][mi][nj] = __builtin_amdgcn_mfma_scale_f32_16x16x128_f8f6f4(
          a[mi], b[nj], acc[Q][mi][nj], 0, 0, 0, 0x7f7f7f7f, 0, 0x7f7f7f7f);
  __builtin_amdgcn_s_setprio(0);
  if (VM) asm volatile("s_waitcnt vmcnt(4)" ::: "memory");
  __builtin_amdgcn_s_barrier();
}

__global__ __launch_bounds__(512, 2) void gemm_mx8(const uint8_t* __restrict__ Aq,
                                                   const uint8_t* __restrict__ BqT,
                                                   float* __restrict__ C,
                                                   const float* __restrict__ sA,
                                                   const float* __restrict__ sB) {
  __shared__ __align__(16) uint8_t lds[131072];

  const int tid = threadIdx.x;
  const int lane = tid & 63;
  const int wid = tid >> 6;
  const int wr = wid >> 2;  // 0..1
  const int wc = wid & 3;   // 0..3
  const int r16 = lane & 15;
  const int hi = lane >> 4;

  // XCD-aware swizzle: 512 wgs, 64 per XCD chunk (bijective, 512%8==0)
  int bid = blockIdx.x;
  int wg = (bid & 7) * 64 + (bid >> 3);
  const long bm = (long)(wg >> 4) * 256;  // 32 M-tiles
  const long bn = (long)(wg & 15) * 256;  // 16 N-tiles

  // scales: force materialization BEFORE staging so their loads never sit in
  // the vmem queue during the counted vmcnt waits.
  float s = sA[0] * sB[0];
  asm volatile("" ::"v"(s));

  // staging invariants: 2 granules per thread per half-tile
  const int gid0 = tid, gid1 = tid + 512;
  const int row0 = gid0 >> 3, row1 = gid1 >> 3;
  const int sc0 = ((gid0 & 7) ^ (row0 & 7)) << 4;
  const int sc1 = ((gid1 & 7) ^ (row1 & 7)) << 4;
  const uint8_t* pA0 = Aq + (bm + row0) * (long)K_DIM + sc0;
  const uint8_t* pA1 = Aq + (bm + row1) * (long)K_DIM + sc1;
  const uint8_t* pB0 = BqT + (bn + row0) * (long)K_DIM + sc0;
  const uint8_t* pB1 = BqT + (bn + row1) * (long)K_DIM + sc1;
  const int ld0 = gid0 * 16, ld1 = gid1 * 16;

#define STG(MAT, H, T, BUF)                                                   \
  do {                                                                        \
    long ko = (long)(((T) & (NT - 1)) * 128) + (long)(H) * (128L * K_DIM);    \
    gload_lds16((MAT ? pB0 : pA0) + ko,                                       \
                lds + (MAT)*65536 + (BUF)*32768 + (H)*16384 + ld0);           \
    gload_lds16((MAT ? pB1 : pA1) + ko,                                       \
                lds + (MAT)*65536 + (BUF)*32768 + (H)*16384 + ld1);           \
  } while (0)

  // fragment read offsets (loop-invariant, swizzled)
  int offA[4][2], offB[2][2];
#pragma unroll
  for (int mi = 0; mi < 4; ++mi) {
    int ra = wr * 64 + mi * 16 + r16;  // 0..127 within half
#pragma unroll
    for (int g = 0; g < 2; ++g) {
      int lg = 2 * hi + g;
      offA[mi][g] = ra * 128 + ((lg ^ (ra & 7)) << 4);
    }
  }
#pragma unroll
  for (int nj = 0; nj < 2; ++nj) {
    int rb = wc * 32 + nj * 16 + r16;  // 0..127 within half
#pragma unroll
    for (int g = 0; g < 2; ++g) {
      int lg = 2 * hi + g;
      offB[nj][g] = rb * 128 + ((lg ^ (rb & 7)) << 4);
    }
  }

  f32x4 acc[4][4][2] = {};

  // ---- prologue: tile0 fully (oldest 8 ops), then Ah0(1), Bh1(1) ----
  STG(0, 0, 0, 0);  // Ah0(0)
  STG(0, 1, 0, 0);  // Ah1(0)
  STG(1, 0, 0, 0);  // Bh0(0)
  STG(1, 1, 0, 0);  // Bh1(0)
  STG(0, 0, 1, 1);  // Ah0(1)  (stream slot "P7 of iter -1")
  STG(1, 1, 1, 1);  // Bh1(1)  (stream slot "P8 of iter -1")
  asm volatile("s_waitcnt vmcnt(4)" ::: "memory");  // tile0 complete
  __builtin_amdgcn_s_barrier();

  // ---- main loop: 2 K-tiles (8 phases) per iteration ----
  for (int i = 0; i < NT / 2; ++i) {
    int T = 2 * i;
    // tile T from buf0, quadrants (0,0),(0,1),(1,1),(1,0)
    phase<0, 0, 0, 0, 0, 1, 1, 0>(lds, offA, offB, acc, T + 1, pA0, pA1, pB0, pB1, ld0, ld1);  // Ah1(T+1)->b1
    phase<1, 0, 1, 0, 1, 0, 1, 0>(lds, offA, offB, acc, T + 1, pA0, pA1, pB0, pB1, ld0, ld1);  // Bh0(T+1)->b1
    phase<3, 1, 1, 0, 0, 0, 0, 0>(lds, offA, offB, acc, T + 2, pA0, pA1, pB0, pB1, ld0, ld1);  // Ah0(T+2)->b0
    phase<2, 1, 0, 0, 1, 1, 0, 1>(lds, offA, offB, acc, T + 2, pA0, pA1, pB0, pB1, ld0, ld1);  // Bh1(T+2)->b0, vmcnt(4)
    // tile T+1 from buf1
    phase<0, 0, 0, 1, 0, 1, 0, 0>(lds, offA, offB, acc, T + 2, pA0, pA1, pB0, pB1, ld0, ld1);  // Ah1(T+2)->b0
    phase<1, 0, 1, 1, 1, 0, 0, 0>(lds, offA, offB, acc, T + 2, pA0, pA1, pB0, pB1, ld0, ld1);  // Bh0(T+2)->b0
    phase<3, 1, 1, 1, 0, 0, 1, 0>(lds, offA, offB, acc, T + 3, pA0, pA1, pB0, pB1, ld0, ld1);  // Ah0(T+3)->b1
    phase<2, 1, 0, 1, 1, 1, 1, 1>(lds, offA, offB, acc, T + 3, pA0, pA1, pB0, pB1, ld0, ld1);  // Bh1(T+3)->b1, vmcnt(4)
  }
#undef STG

  // ---- epilogue: C-write ----
#pragma unroll
  for (int MQ = 0; MQ < 2; ++MQ)
#pragma unroll
    for (int NQ = 0; NQ < 2; ++NQ)
#pragma unroll
      for (int mi = 0; mi < 4; ++mi)
#pragma unroll
        for (int nj = 0; nj < 2; ++nj) {
          long row = bm + MQ * 128 + wr * 64 + mi * 16 + hi * 4;
          long col = bn + NQ * 128 + wc * 32 + nj * 16 + r16;
          float* cp = C + row * N_DIM + col;
          f32x4 v = acc[MQ * 2 + NQ][mi][nj];
#pragma unroll
          for (int e = 0; e < 4; ++e) cp[(long)e * N_DIM] = v[e] * s;
        }
}

// ---------- launcher ----------

extern "C" void kernel_launch(void* const* d_in, const int* in_sizes, int n_in,
                              void* d_out, int out_size, void* d_ws, size_t ws_size,
                              hipStream_t stream) {
  const float* A = (const float*)d_in[0];   // (8192, 4096)
  const float* B = (const float*)d_in[1];   // (4096, 4096)
  const float* sA = (const float*)d_in[2];  // input_scale
  const float* sB = (const float*)d_in[4];  // kernel_scale
  float* out = (float*)d_out;

  uint8_t* Aq = (uint8_t*)d_ws;               // M*K fp8
  uint8_t* BqT = Aq + (size_t)M_DIM * K_DIM;  // N*K fp8 (transposed)

  int nv4_a = M_DIM * K_DIM / 4;
  quant_a<<<nv4_a / 1024, 256, 0, stream>>>(A, (u32*)Aq, sA, nv4_a);
  quant_b_t<<<dim3(K_DIM / 64, N_DIM / 64), 256, 0, stream>>>(B, BqT, sB);
  gemm_mx8<<<dim3((M_DIM / 256) * (N_DIM / 256)), 512, 0, stream>>>(Aq, BqT, out, sA, sB);
}